// Round 1
// 306.217 us; speedup vs baseline: 1.0652x; 1.0652x over previous
//
#include <hip/hip_runtime.h>
#include <math.h>

namespace {

constexpr int H = 2048;
constexpr int W = 2048;
constexpr float TANH_C  = 1.1486328125f;
constexpr float DEG2RAD = 0.017453292519943295f; // np.float32(pi/180)
constexpr float RT2H    = 0.70710678118654752f;  // sqrt(2)/2
constexpr float LOG2E   = 1.4426950408889634f;   // log2(e)
constexpr float TWOPI   = 6.283185307179586f;

// --- guarded HW-transcendental wrappers (all lower to a single VALU op) ---
__device__ __forceinline__ float fexp2(float x) {
#if __has_builtin(__builtin_amdgcn_exp2f)
    return __builtin_amdgcn_exp2f(x);          // v_exp_f32: 2^x
#else
    return __exp2f(x);
#endif
}
__device__ __forceinline__ float fcos_rev(float x) {  // cos(2*pi*x)
#if __has_builtin(__builtin_amdgcn_cosf)
    return __builtin_amdgcn_cosf(x);           // v_cos_f32: input in revolutions
#else
    return __cosf(x * TWOPI);
#endif
}
__device__ __forceinline__ float fsin_rev(float x) {  // sin(2*pi*x)
#if __has_builtin(__builtin_amdgcn_sinf)
    return __builtin_amdgcn_sinf(x);
#else
    return __sinf(x * TWOPI);
#endif
}
__device__ __forceinline__ float frcp(float x) {
#if __has_builtin(__builtin_amdgcn_rcpf)
    return __builtin_amdgcn_rcpf(x);           // v_rcp_f32 (~1 ulp)
#else
    return 1.0f / x;
#endif
}

// out layout: [0,HW) p_ignite, [HW,2HW) new_burning (0/1), [2HW,3HW) new_burned
__global__ __launch_bounds__(256) void wildfire_step(
    const float* __restrict__ p_veg,  const float* __restrict__ p_den,
    const float* __restrict__ wind_v, const float* __restrict__ wind_d,
    const float* __restrict__ slope,
    const float* __restrict__ s_a,  const float* __restrict__ s_ph,
    const float* __restrict__ s_c1, const float* __restrict__ s_c2,
    const float* __restrict__ s_pc,
    const float* __restrict__ rand_ig, const float* __restrict__ rand_co,
    const int* __restrict__ burning, const int* __restrict__ burned,
    float* __restrict__ out)
{
    __shared__ float sb[3][260];           // burning halo: rows i-1..i+1, cols j0-1..j0+256
    const int t  = (int)threadIdx.x;
    const int i  = (int)blockIdx.y;
    const int j0 = (int)blockIdx.x * 256;
    const int j  = j0 + t;

    for (int r = 0; r < 3; ++r) {
        const int ii = i + r - 1;
        for (int c = t; c < 258; c += 256) {
            const int jj = j0 - 1 + c;
            float v = 0.f;
            if (ii >= 0 && ii < H && jj >= 0 && jj < W)
                v = burning[ii * W + jj] ? 1.f : 0.f;
            sb[r][c] = v;
        }
    }
    __syncthreads();

    // 3x3 burning window (window pos (r,c) -> slope index r*3+c)
    const float b0 = sb[0][t], b1 = sb[0][t+1], b2 = sb[0][t+2];
    const float b3 = sb[1][t], bc = sb[1][t+1], b5 = sb[1][t+2];
    const float b6 = sb[2][t], b7 = sb[2][t+1], b8 = sb[2][t+2];

    const int   idx        = i * W + j;
    const bool  is_burning = (bc != 0.f);
    const int   was_burned = burned[idx];
    const float rco        = rand_co[idx];
    const float p_cont     = s_pc[0];
    const float a    = s_a[0];
    const float p_h  = s_ph[0];
    const float c1   = s_c1[0];
    const float c2   = s_c2[0];

    // any_n is exactly the count of burning neighbors (each b is 0.0 or 1.0)
    const float any_n = ((b0 + b1) + (b2 + b3)) + ((b5 + b6) + (b7 + b8));

    float p_ignite    = 0.f;
    bool  new_ignited = false;

    // PER-LANE gate: whole wave still skips via s_cbranch_execz when no lane
    // is active, but in mixed waves the exec-masked lanes issue NO loads —
    // only ~7.7% of cells fetch the heavy fields + 36B slope.
    if (any_n != 0.f) {
        const float pv  = p_veg[idx];
        const float pd  = p_den[idx];
        const float wv  = wind_v[idx];
        const float wd  = wind_d[idx];
        const float rig = rand_ig[idx];
        const float* sp = slope + (size_t)idx * 9;
        const float sl0 = sp[0], sl1 = sp[1], sl2 = sp[2];
        const float sl3 = sp[3], sl5 = sp[5];
        const float sl6 = sp[6], sl7 = sp[7], sl8 = sp[8];

        // cos/sin of wind angle: HW units are revolutions -> wd/360 directly
        const float wrev = wd * (1.f / 360.f);
        const float cw = fcos_rev(wrev);
        const float sw = fsin_rev(wrev);

        // Everything in log2 space so every exp is a bare v_exp_f32:
        //   2*L*z_k = Cz2 * 2^(q_k),  q_k = L*c2*wv*ct_k + L*a*DEG2RAD*sl_k
        //   Cz2 = 2*L*TANH_C*p_base * 2^(L*(c1*wv - c2*wv))
        //   E_k = exp(2 z_k) = 2^(2*L*z_k)
        //   p_ignite = 1 - 2^m / prod_k (1 + b_k*E_k),  m = #burning nbrs
        const float Lc2wv = (LOG2E * c2) * wv;
        const float cwv = Lc2wv * cw, swv = Lc2wv * sw;
        const float cwr = RT2H * cwv, swr = RT2H * swv;
        const float dpl = cwr + swr;   // for  45 deg
        const float dmi = cwr - swr;   // for 315 deg
        const float aslL = (a * DEG2RAD) * LOG2E;
        const float p_base = (p_h * (1.f + pv)) * (1.f + pd);
        const float Cz2 = (2.f * LOG2E * TANH_C) * p_base
                        * fexp2(LOG2E * (c1 * wv - c2 * wv));

        // 4 VALU + 2 v_exp per neighbor (sign of T folds into the fma modifier)
#define NEIGHBOR(K, b, T, sl)                                            \
        const float q##K = fmaf(aslL, (sl), (T));                        \
        const float z##K = Cz2 * fexp2(q##K);                            \
        const float E##K = fexp2(z##K);                                  \
        const float d##K = fmaf((b), E##K, 1.f);

        NEIGHBOR(0, b0,  dmi, sl0)   // 315: ct = RT2H*(cw-sw)
        NEIGHBOR(1, b1, -swv, sl1)   // 270: ct = -sw
        NEIGHBOR(2, b2, -dpl, sl2)   // 225: ct = -RT2H*(cw+sw)
        NEIGHBOR(3, b3,  cwv, sl3)   //   0: ct =  cw
        NEIGHBOR(5, b5, -cwv, sl5)   // 180: ct = -cw
        NEIGHBOR(6, b6,  dpl, sl6)   //  45: ct =  RT2H*(cw+sw)
        NEIGHBOR(7, b7,  swv, sl7)   //  90: ct =  sw
        NEIGHBOR(8, b8, -dmi, sl8)   // 135: ct =  RT2H*(sw-cw)
#undef NEIGHBOR
        const float den = ((d0 * d1) * (d2 * d3)) * ((d5 * d6) * (d7 * d8));
        const float num = fexp2(any_n);          // 2^m exactly (m integer-valued)
        p_ignite = fmaf(-num, frcp(den), 1.f);

        new_ignited = (!is_burning) && (was_burned == 0) && (rig < p_ignite);
    }

    const bool keep = is_burning && (rco < p_cont);
    const bool nb   = new_ignited || keep;
    const bool nd   = (was_burned != 0) || (is_burning && !keep);

    out[idx]             = p_ignite;
    out[H * W + idx]     = nb ? 1.f : 0.f;
    out[2 * H * W + idx] = nd ? 1.f : 0.f;
}

} // namespace

extern "C" void kernel_launch(void* const* d_in, const int* in_sizes, int n_in,
                              void* d_out, int out_size, void* d_ws, size_t ws_size,
                              hipStream_t stream)
{
    (void)in_sizes; (void)n_in; (void)out_size; (void)d_ws; (void)ws_size;
    dim3 grid(W / 256, H, 1);
    dim3 block(256, 1, 1);
    hipLaunchKernelGGL(wildfire_step, grid, block, 0, stream,
        (const float*)d_in[0],  (const float*)d_in[1],
        (const float*)d_in[2],  (const float*)d_in[3],
        (const float*)d_in[4],
        (const float*)d_in[5],  (const float*)d_in[6],
        (const float*)d_in[7],  (const float*)d_in[8],
        (const float*)d_in[9],
        (const float*)d_in[10], (const float*)d_in[11],
        (const int*)d_in[12],   (const int*)d_in[13],
        (float*)d_out);
}